// Round 1
// baseline (813.257 us; speedup 1.0000x reference)
//
#include <hip/hip_runtime.h>

#define IN_C 64
#define HID_C 64
#define OUT_C 32

// ---------------------------------------------------------------------------
// Edge-index format detection: reference dtype is int64, harness doc suggests
// int32. If the buffer is little-endian int64 with values in [0, N), every
// odd int32 word is 0. If int32, odd words are random node ids (~1e-5 chance
// of a single zero). Sample 4096 odd words; all-zero => int64.
// ---------------------------------------------------------------------------
__global__ void detect_fmt(const int* ei32, int* flag, int n_check) {
    __shared__ int s_any;
    if (threadIdx.x == 0) s_any = 0;
    __syncthreads();
    int any = 0;
    for (int i = threadIdx.x; i < n_check; i += blockDim.x) {
        if (ei32[2 * i + 1] != 0) any = 1;
    }
    if (any) atomicOr(&s_any, 1);
    __syncthreads();
    if (threadIdx.x == 0) *flag = (s_any == 0) ? 1 : 0;  // 1 => int64
}

__device__ __forceinline__ int ld_edge(const void* ei, int idx, int is64) {
    if (is64) return (int)((const long long*)ei)[idx];
    return ((const int*)ei)[idx];
}

// deg[dst] counts (real edges only; +1 self-loop added in scan)
__global__ void count_deg(const void* ei, int E, const int* flag, int* deg) {
    int e = blockIdx.x * blockDim.x + threadIdx.x;
    if (e >= E) return;
    int is64 = *flag;
    int dst = ld_edge(ei, E + e, is64);
    atomicAdd(&deg[dst], 1);
}

// Single-block exclusive scan over deg -> offs, cursor; also dinv = (deg+1)^-0.5
__global__ void scan_deg(const int* deg, int* offs, int* cursor, float* dinv, int n) {
    __shared__ int ssum[1024];
    int tid = threadIdx.x;
    int chunk = (n + 1023) / 1024;
    int start = tid * chunk;
    int end = start + chunk;
    if (end > n) end = n;
    int s = 0;
    for (int i = start; i < end; i++) s += deg[i];
    ssum[tid] = s;
    __syncthreads();
    for (int o = 1; o < 1024; o <<= 1) {
        int v = (tid >= o) ? ssum[tid - o] : 0;
        __syncthreads();
        ssum[tid] += v;
        __syncthreads();
    }
    int prefix = (tid == 0) ? 0 : ssum[tid - 1];
    for (int i = start; i < end; i++) {
        int d = deg[i];
        offs[i] = prefix;
        cursor[i] = prefix;
        dinv[i] = rsqrtf((float)(d + 1));
        prefix += d;
    }
    if (tid == 1023) offs[n] = ssum[1023];
}

// Counting-sort edges into CSR-by-destination; store source row + edge norm.
__global__ void place_edges(const void* ei, int E, const int* flag, int* cursor,
                            const float* dinv, int* row_s, float* norm_s) {
    int e = blockIdx.x * blockDim.x + threadIdx.x;
    if (e >= E) return;
    int is64 = *flag;
    int src = ld_edge(ei, e, is64);
    int dst = ld_edge(ei, E + e, is64);
    int p = atomicAdd(&cursor[dst], 1);
    row_s[p] = src;
    norm_s[p] = dinv[src] * dinv[dst];
}

// out[n,0:64] = (relu_in ? relu(in) : in)[n,0:64] @ W(64x64). 4 rows/block.
__global__ void gemm64(const float* __restrict__ in, const float* __restrict__ W,
                       float* __restrict__ out, int n, int relu_in) {
    __shared__ float sW[64 * 64];
    __shared__ float sIn[4][64];
    int tid = threadIdx.x;
    for (int i = tid; i < 64 * 64; i += 256) sW[i] = W[i];
    int r = tid >> 6;  // 0..3 (wave id)
    int c = tid & 63;  // lane
    int row = blockIdx.x * 4 + r;
    float v = 0.f;
    if (row < n) v = in[row * 64 + c];
    if (relu_in) v = fmaxf(v, 0.f);
    sIn[r][c] = v;
    __syncthreads();
    float acc = 0.f;
#pragma unroll
    for (int k = 0; k < 64; k++) acc = fmaf(sIn[r][k], sW[k * 64 + c], acc);
    if (row < n) out[row * 64 + c] = acc;
}

// acc[n,c] = b[c] + t[n,c]*dinv[n]^2 + sum_{edges->n} t[row,c]*norm
// One wave per node, lane = channel. Coalesced 256B gather per edge.
__global__ void aggregate(const float* __restrict__ t, const int* __restrict__ offs,
                          const int* __restrict__ row_s, const float* __restrict__ norm_s,
                          const float* __restrict__ dinv, const float* __restrict__ bias,
                          float* __restrict__ acc, int n) {
    int wave = (blockIdx.x * blockDim.x + threadIdx.x) >> 6;
    int lane = threadIdx.x & 63;
    if (wave >= n) return;
    int beg = offs[wave], end = offs[wave + 1];
    float d = dinv[wave];
    float s = fmaf(t[wave * 64 + lane], d * d, bias[lane]);
    int j = beg;
    for (; j + 4 <= end; j += 4) {
        int r0 = row_s[j], r1 = row_s[j + 1], r2 = row_s[j + 2], r3 = row_s[j + 3];
        float w0 = norm_s[j], w1 = norm_s[j + 1], w2 = norm_s[j + 2], w3 = norm_s[j + 3];
        float v0 = t[r0 * 64 + lane];
        float v1 = t[r1 * 64 + lane];
        float v2 = t[r2 * 64 + lane];
        float v3 = t[r3 * 64 + lane];
        s = fmaf(v0, w0, s);
        s = fmaf(v1, w1, s);
        s = fmaf(v2, w2, s);
        s = fmaf(v3, w3, s);
    }
    for (; j < end; j++) s = fmaf(t[row_s[j] * 64 + lane], norm_s[j], s);
    acc[wave * 64 + lane] = s;
}

// out[n,0:32] = relu(in)[n,0:64] @ Wlin(64x32) + blin. 8 rows/block.
__global__ void gemm32(const float* __restrict__ in, const float* __restrict__ W,
                       const float* __restrict__ b, float* __restrict__ out, int n) {
    __shared__ float sW[64 * 32];
    __shared__ float sIn[8][64];
    int tid = threadIdx.x;
    for (int i = tid; i < 64 * 32; i += 256) sW[i] = W[i];
    for (int i = tid; i < 8 * 64; i += 256) {
        int rr = i >> 6, cc = i & 63;
        int g = blockIdx.x * 8 + rr;
        float v = (g < n) ? in[g * 64 + cc] : 0.f;
        sIn[rr][cc] = fmaxf(v, 0.f);
    }
    __syncthreads();
    int r = tid >> 5, c = tid & 31;
    int row = blockIdx.x * 8 + r;
    float acc = b[c];
#pragma unroll
    for (int k = 0; k < 64; k++) acc = fmaf(sIn[r][k], sW[k * 32 + c], acc);
    if (row < n) out[row * 32 + c] = acc;
}

extern "C" void kernel_launch(void* const* d_in, const int* in_sizes, int n_in,
                              void* d_out, int out_size, void* d_ws, size_t ws_size,
                              hipStream_t stream) {
    (void)n_in; (void)out_size; (void)ws_size;
    const float* x    = (const float*)d_in[0];
    const void*  ei   = d_in[1];
    const float* W1   = (const float*)d_in[2];
    const float* b1   = (const float*)d_in[3];
    const float* W2   = (const float*)d_in[4];
    const float* b2   = (const float*)d_in[5];
    const float* Wlin = (const float*)d_in[6];
    const float* blin = (const float*)d_in[7];
    float* out = (float*)d_out;

    const int N = in_sizes[0] / IN_C;
    const int E = in_sizes[1] / 2;

    // Workspace layout (256B-aligned chunks), total ~66 MB.
    char* ws = (char*)d_ws;
    size_t off = 0;
    auto alloc = [&](size_t bytes) -> void* {
        size_t a = (off + 255) & ~(size_t)255;
        off = a + bytes;
        return (void*)(ws + a);
    };
    int*   flag   = (int*)  alloc(4);
    int*   deg    = (int*)  alloc((size_t)N * 4);
    int*   offs   = (int*)  alloc((size_t)(N + 1) * 4);
    int*   cursor = (int*)  alloc((size_t)N * 4);
    float* dinv   = (float*)alloc((size_t)N * 4);
    int*   row_s  = (int*)  alloc((size_t)E * 4);
    float* norm_s = (float*)alloc((size_t)E * 4);
    float* tbuf   = (float*)alloc((size_t)N * HID_C * 4);
    float* acc    = (float*)alloc((size_t)N * HID_C * 4);

    hipMemsetAsync(deg, 0, (size_t)N * 4, stream);

    int n_check = E < 4096 ? E : 4096;
    detect_fmt<<<1, 256, 0, stream>>>((const int*)ei, flag, n_check);
    count_deg<<<(E + 255) / 256, 256, 0, stream>>>(ei, E, flag, deg);
    scan_deg<<<1, 1024, 0, stream>>>(deg, offs, cursor, dinv, N);
    place_edges<<<(E + 255) / 256, 256, 0, stream>>>(ei, E, flag, cursor, dinv, row_s, norm_s);

    gemm64<<<(N + 3) / 4, 256, 0, stream>>>(x, W1, tbuf, N, 0);
    aggregate<<<(N + 3) / 4, 256, 0, stream>>>(tbuf, offs, row_s, norm_s, dinv, b1, acc, N);
    gemm64<<<(N + 3) / 4, 256, 0, stream>>>(acc, W2, tbuf, N, 1);
    aggregate<<<(N + 3) / 4, 256, 0, stream>>>(tbuf, offs, row_s, norm_s, dinv, b2, acc, N);
    gemm32<<<(N + 7) / 8, 256, 0, stream>>>(acc, Wlin, blin, out, N);
}

// Round 2
// 510.142 us; speedup vs baseline: 1.5942x; 1.5942x over previous
//
#include <hip/hip_runtime.h>

#define IN_C 64
#define HID_C 64
#define OUT_C 32
#define SCAN_CHUNK 512  // elements per block in the device-wide scan

// ---------------------------------------------------------------------------
// Edge-index format detection: reference dtype is int64, harness doc suggests
// int32. If the buffer is little-endian int64 with values in [0, N), every
// odd int32 word is 0. Sample 4096 odd words; all-zero => int64.
// ---------------------------------------------------------------------------
__global__ void detect_fmt(const int* ei32, int* flag, int n_check) {
    __shared__ int s_any;
    if (threadIdx.x == 0) s_any = 0;
    __syncthreads();
    int any = 0;
    for (int i = threadIdx.x; i < n_check; i += blockDim.x) {
        if (ei32[2 * i + 1] != 0) any = 1;
    }
    if (any) atomicOr(&s_any, 1);
    __syncthreads();
    if (threadIdx.x == 0) *flag = (s_any == 0) ? 1 : 0;  // 1 => int64
}

__device__ __forceinline__ int ld_edge(const void* ei, int idx, int is64) {
    if (is64) return (int)((const long long*)ei)[idx];
    return ((const int*)ei)[idx];
}

// deg[dst] counts (real edges only; +1 self-loop handled via dinv/diag term)
__global__ void count_deg(const void* ei, int E, const int* flag, int* deg) {
    int e = blockIdx.x * blockDim.x + threadIdx.x;
    if (e >= E) return;
    int is64 = *flag;
    int dst = ld_edge(ei, E + e, is64);
    atomicAdd(&deg[dst], 1);
}

// ---------------------------------------------------------------------------
// Device-wide exclusive scan of deg[0..n) in 3 phases (replaces the 280us
// single-block scan: 1 block / 0.14% occupancy was 34% of total runtime).
// ---------------------------------------------------------------------------
// Phase A: per-block reduction of a SCAN_CHUNK-element chunk.
__global__ void block_sums(const int* __restrict__ deg, int* __restrict__ bsum, int n) {
    __shared__ int red[256];
    int base = blockIdx.x * SCAN_CHUNK;
    int tid = threadIdx.x;
    int i0 = base + 2 * tid, i1 = i0 + 1;
    int s = 0;
    if (i0 < n) s += deg[i0];
    if (i1 < n) s += deg[i1];
    red[tid] = s;
    __syncthreads();
    for (int o = 128; o > 0; o >>= 1) {
        if (tid < o) red[tid] += red[tid + o];
        __syncthreads();
    }
    if (tid == 0) bsum[blockIdx.x] = red[0];
}

// Phase B: single small block scans nb (<=1024) block sums -> exclusive bpre;
// also writes offs[n] = grand total.
__global__ void scan_bsums(const int* __restrict__ bsum, int* __restrict__ bpre,
                           int* __restrict__ offs, int nb, int n) {
    __shared__ int s[1024];
    int tid = threadIdx.x;
    s[tid] = (tid < nb) ? bsum[tid] : 0;
    __syncthreads();
    for (int o = 1; o < 1024; o <<= 1) {
        int v = (tid >= o) ? s[tid - o] : 0;
        __syncthreads();
        s[tid] += v;
        __syncthreads();
    }
    if (tid < nb) bpre[tid] = (tid == 0) ? 0 : s[tid - 1];
    if (tid == 1023) offs[n] = s[1023];
}

// Phase C: re-read chunk, intra-block exclusive scan, add block prefix,
// emit offs / cursor / dinv.
__global__ void write_offs(const int* __restrict__ deg, const int* __restrict__ bpre,
                           int* __restrict__ offs, int* __restrict__ cursor,
                           float* __restrict__ dinv, int n) {
    __shared__ int tsum[256];
    int base = blockIdx.x * SCAN_CHUNK;
    int tid = threadIdx.x;
    int i0 = base + 2 * tid, i1 = i0 + 1;
    int d0 = (i0 < n) ? deg[i0] : 0;
    int d1 = (i1 < n) ? deg[i1] : 0;
    tsum[tid] = d0 + d1;
    __syncthreads();
    for (int o = 1; o < 256; o <<= 1) {
        int v = (tid >= o) ? tsum[tid - o] : 0;
        __syncthreads();
        tsum[tid] += v;
        __syncthreads();
    }
    int pre = bpre[blockIdx.x] + ((tid == 0) ? 0 : tsum[tid - 1]);
    if (i0 < n) {
        offs[i0] = pre;
        cursor[i0] = pre;
        dinv[i0] = rsqrtf((float)(d0 + 1));
    }
    if (i1 < n) {
        offs[i1] = pre + d0;
        cursor[i1] = pre + d0;
        dinv[i1] = rsqrtf((float)(d1 + 1));
    }
}

// Counting-sort edges into CSR-by-destination; store source row + edge norm.
__global__ void place_edges(const void* ei, int E, const int* flag, int* cursor,
                            const float* dinv, int* row_s, float* norm_s) {
    int e = blockIdx.x * blockDim.x + threadIdx.x;
    if (e >= E) return;
    int is64 = *flag;
    int src = ld_edge(ei, e, is64);
    int dst = ld_edge(ei, E + e, is64);
    int p = atomicAdd(&cursor[dst], 1);
    row_s[p] = src;
    norm_s[p] = dinv[src] * dinv[dst];
}

// out[n,0:64] = (relu_in ? relu(in) : in)[n,0:64] @ W(64x64). 4 rows/block.
__global__ void gemm64(const float* __restrict__ in, const float* __restrict__ W,
                       float* __restrict__ out, int n, int relu_in) {
    __shared__ float sW[64 * 64];
    __shared__ float sIn[4][64];
    int tid = threadIdx.x;
    for (int i = tid; i < 64 * 64; i += 256) sW[i] = W[i];
    int r = tid >> 6;  // 0..3 (wave id)
    int c = tid & 63;  // lane
    int row = blockIdx.x * 4 + r;
    float v = 0.f;
    if (row < n) v = in[row * 64 + c];
    if (relu_in) v = fmaxf(v, 0.f);
    sIn[r][c] = v;
    __syncthreads();
    float acc = 0.f;
#pragma unroll
    for (int k = 0; k < 64; k++) acc = fmaf(sIn[r][k], sW[k * 64 + c], acc);
    if (row < n) out[row * 64 + c] = acc;
}

// acc[n,c] = b[c] + t[n,c]*dinv[n]^2 + sum_{edges->n} t[row,c]*norm
// One wave per node, lane = channel. Coalesced 256B gather per edge.
__global__ void aggregate(const float* __restrict__ t, const int* __restrict__ offs,
                          const int* __restrict__ row_s, const float* __restrict__ norm_s,
                          const float* __restrict__ dinv, const float* __restrict__ bias,
                          float* __restrict__ acc, int n) {
    int wave = (blockIdx.x * blockDim.x + threadIdx.x) >> 6;
    int lane = threadIdx.x & 63;
    if (wave >= n) return;
    int beg = offs[wave], end = offs[wave + 1];
    float d = dinv[wave];
    float s = fmaf(t[wave * 64 + lane], d * d, bias[lane]);
    int j = beg;
    for (; j + 4 <= end; j += 4) {
        int r0 = row_s[j], r1 = row_s[j + 1], r2 = row_s[j + 2], r3 = row_s[j + 3];
        float w0 = norm_s[j], w1 = norm_s[j + 1], w2 = norm_s[j + 2], w3 = norm_s[j + 3];
        float v0 = t[r0 * 64 + lane];
        float v1 = t[r1 * 64 + lane];
        float v2 = t[r2 * 64 + lane];
        float v3 = t[r3 * 64 + lane];
        s = fmaf(v0, w0, s);
        s = fmaf(v1, w1, s);
        s = fmaf(v2, w2, s);
        s = fmaf(v3, w3, s);
    }
    for (; j < end; j++) s = fmaf(t[row_s[j] * 64 + lane], norm_s[j], s);
    acc[wave * 64 + lane] = s;
}

// out[n,0:32] = relu(in)[n,0:64] @ Wlin(64x32) + blin. 8 rows/block.
__global__ void gemm32(const float* __restrict__ in, const float* __restrict__ W,
                       const float* __restrict__ b, float* __restrict__ out, int n) {
    __shared__ float sW[64 * 32];
    __shared__ float sIn[8][64];
    int tid = threadIdx.x;
    for (int i = tid; i < 64 * 32; i += 256) sW[i] = W[i];
    for (int i = tid; i < 8 * 64; i += 256) {
        int rr = i >> 6, cc = i & 63;
        int g = blockIdx.x * 8 + rr;
        float v = (g < n) ? in[g * 64 + cc] : 0.f;
        sIn[rr][cc] = fmaxf(v, 0.f);
    }
    __syncthreads();
    int r = tid >> 5, c = tid & 31;
    int row = blockIdx.x * 8 + r;
    float acc = b[c];
#pragma unroll
    for (int k = 0; k < 64; k++) acc = fmaf(sIn[r][k], sW[k * 32 + c], acc);
    if (row < n) out[row * 32 + c] = acc;
}

extern "C" void kernel_launch(void* const* d_in, const int* in_sizes, int n_in,
                              void* d_out, int out_size, void* d_ws, size_t ws_size,
                              hipStream_t stream) {
    (void)n_in; (void)out_size; (void)ws_size;
    const float* x    = (const float*)d_in[0];
    const void*  ei   = d_in[1];
    const float* W1   = (const float*)d_in[2];
    const float* b1   = (const float*)d_in[3];
    const float* W2   = (const float*)d_in[4];
    const float* b2   = (const float*)d_in[5];
    const float* Wlin = (const float*)d_in[6];
    const float* blin = (const float*)d_in[7];
    float* out = (float*)d_out;

    const int N = in_sizes[0] / IN_C;
    const int E = in_sizes[1] / 2;
    const int NB = (N + SCAN_CHUNK - 1) / SCAN_CHUNK;  // scan blocks (196 @ N=100k)

    // Workspace layout (256B-aligned chunks), total ~66 MB.
    char* ws = (char*)d_ws;
    size_t off = 0;
    auto alloc = [&](size_t bytes) -> void* {
        size_t a = (off + 255) & ~(size_t)255;
        off = a + bytes;
        return (void*)(ws + a);
    };
    int*   flag   = (int*)  alloc(4);
    int*   deg    = (int*)  alloc((size_t)N * 4);
    int*   offs   = (int*)  alloc((size_t)(N + 1) * 4);
    int*   cursor = (int*)  alloc((size_t)N * 4);
    float* dinv   = (float*)alloc((size_t)N * 4);
    int*   bsum   = (int*)  alloc((size_t)NB * 4);
    int*   bpre   = (int*)  alloc((size_t)NB * 4);
    int*   row_s  = (int*)  alloc((size_t)E * 4);
    float* norm_s = (float*)alloc((size_t)E * 4);
    float* tbuf   = (float*)alloc((size_t)N * HID_C * 4);
    float* acc    = (float*)alloc((size_t)N * HID_C * 4);

    hipMemsetAsync(deg, 0, (size_t)N * 4, stream);

    int n_check = E < 4096 ? E : 4096;
    detect_fmt<<<1, 256, 0, stream>>>((const int*)ei, flag, n_check);
    count_deg<<<(E + 255) / 256, 256, 0, stream>>>(ei, E, flag, deg);
    block_sums<<<NB, 256, 0, stream>>>(deg, bsum, N);
    scan_bsums<<<1, 1024, 0, stream>>>(bsum, bpre, offs, NB, N);
    write_offs<<<NB, 256, 0, stream>>>(deg, bpre, offs, cursor, dinv, N);
    place_edges<<<(E + 255) / 256, 256, 0, stream>>>(ei, E, flag, cursor, dinv, row_s, norm_s);

    gemm64<<<(N + 3) / 4, 256, 0, stream>>>(x, W1, tbuf, N, 0);
    aggregate<<<(N + 3) / 4, 256, 0, stream>>>(tbuf, offs, row_s, norm_s, dinv, b1, acc, N);
    gemm64<<<(N + 3) / 4, 256, 0, stream>>>(acc, W2, tbuf, N, 1);
    aggregate<<<(N + 3) / 4, 256, 0, stream>>>(tbuf, offs, row_s, norm_s, dinv, b2, acc, N);
    gemm32<<<(N + 7) / 8, 256, 0, stream>>>(acc, Wlin, blin, out, N);
}

// Round 3
// 505.285 us; speedup vs baseline: 1.6095x; 1.0096x over previous
//
#include <hip/hip_runtime.h>

#define IN_C 64
#define HID_C 64
#define OUT_C 32
#define SCAN_CHUNK 512  // elements per block in the device-wide scan

// ---------------------------------------------------------------------------
// Edge-index format detection: reference dtype is int64, harness doc suggests
// int32. If the buffer is little-endian int64 with values in [0, N), every
// odd int32 word is 0. Sample 4096 odd words; all-zero => int64.
// ---------------------------------------------------------------------------
__global__ void detect_fmt(const int* ei32, int* flag, int n_check) {
    __shared__ int s_any;
    if (threadIdx.x == 0) s_any = 0;
    __syncthreads();
    int any = 0;
    for (int i = threadIdx.x; i < n_check; i += blockDim.x) {
        if (ei32[2 * i + 1] != 0) any = 1;
    }
    if (any) atomicOr(&s_any, 1);
    __syncthreads();
    if (threadIdx.x == 0) *flag = (s_any == 0) ? 1 : 0;  // 1 => int64
}

__device__ __forceinline__ int ld_edge(const void* ei, int idx, int is64) {
    if (is64) return (int)((const long long*)ei)[idx];
    return ((const int*)ei)[idx];
}

// deg[dst] counts (real edges only; self-loop handled via diag term in aggregate)
__global__ void count_deg(const void* ei, int E, const int* flag, int* deg) {
    int e = blockIdx.x * blockDim.x + threadIdx.x;
    if (e >= E) return;
    int is64 = *flag;
    int dst = ld_edge(ei, E + e, is64);
    atomicAdd(&deg[dst], 1);
}

// ---------------------------------------------------------------------------
// Device-wide exclusive scan of deg[0..n) in 3 phases.
// ---------------------------------------------------------------------------
__global__ void block_sums(const int* __restrict__ deg, int* __restrict__ bsum, int n) {
    __shared__ int red[256];
    int base = blockIdx.x * SCAN_CHUNK;
    int tid = threadIdx.x;
    int i0 = base + 2 * tid, i1 = i0 + 1;
    int s = 0;
    if (i0 < n) s += deg[i0];
    if (i1 < n) s += deg[i1];
    red[tid] = s;
    __syncthreads();
    for (int o = 128; o > 0; o >>= 1) {
        if (tid < o) red[tid] += red[tid + o];
        __syncthreads();
    }
    if (tid == 0) bsum[blockIdx.x] = red[0];
}

__global__ void scan_bsums(const int* __restrict__ bsum, int* __restrict__ bpre,
                           int* __restrict__ offs, int nb, int n) {
    __shared__ int s[1024];
    int tid = threadIdx.x;
    s[tid] = (tid < nb) ? bsum[tid] : 0;
    __syncthreads();
    for (int o = 1; o < 1024; o <<= 1) {
        int v = (tid >= o) ? s[tid - o] : 0;
        __syncthreads();
        s[tid] += v;
        __syncthreads();
    }
    if (tid < nb) bpre[tid] = (tid == 0) ? 0 : s[tid - 1];
    if (tid == 1023) offs[n] = s[1023];
}

__global__ void write_offs(const int* __restrict__ deg, const int* __restrict__ bpre,
                           int* __restrict__ offs, int* __restrict__ cursor,
                           float* __restrict__ dinv, int n) {
    __shared__ int tsum[256];
    int base = blockIdx.x * SCAN_CHUNK;
    int tid = threadIdx.x;
    int i0 = base + 2 * tid, i1 = i0 + 1;
    int d0 = (i0 < n) ? deg[i0] : 0;
    int d1 = (i1 < n) ? deg[i1] : 0;
    tsum[tid] = d0 + d1;
    __syncthreads();
    for (int o = 1; o < 256; o <<= 1) {
        int v = (tid >= o) ? tsum[tid - o] : 0;
        __syncthreads();
        tsum[tid] += v;
        __syncthreads();
    }
    int pre = bpre[blockIdx.x] + ((tid == 0) ? 0 : tsum[tid - 1]);
    if (i0 < n) {
        offs[i0] = pre;
        cursor[i0] = pre;
        dinv[i0] = rsqrtf((float)(d0 + 1));
    }
    if (i1 < n) {
        offs[i1] = pre + d0;
        cursor[i1] = pre + d0;
        dinv[i1] = rsqrtf((float)(d1 + 1));
    }
}

// Counting-sort edges into CSR-by-destination. Single combined int2 record
// {src, norm} per edge: ONE scattered 8B store instead of two 4B stores to
// two arrays (R2: WRITE_SIZE was 155 MB for 12.8 MB of payload — each
// partial-line touch costs a 64B line; halve the touched lines).
__global__ void place_edges(const void* ei, int E, const int* flag, int* cursor,
                            const float* dinv, int2* __restrict__ rec) {
    int e = blockIdx.x * blockDim.x + threadIdx.x;
    if (e >= E) return;
    int is64 = *flag;
    int src = ld_edge(ei, e, is64);
    int dst = ld_edge(ei, E + e, is64);
    int p = atomicAdd(&cursor[dst], 1);
    float nrm = dinv[src] * dinv[dst];
    rec[p] = make_int2(src, __float_as_int(nrm));
}

// out[n,0:64] = (relu_in ? relu(in) : in)[n,0:64] @ W(64x64). 4 rows/block.
__global__ void gemm64(const float* __restrict__ in, const float* __restrict__ W,
                       float* __restrict__ out, int n, int relu_in) {
    __shared__ float sW[64 * 64];
    __shared__ float sIn[4][64];
    int tid = threadIdx.x;
    for (int i = tid; i < 64 * 64; i += 256) sW[i] = W[i];
    int r = tid >> 6;  // 0..3 (wave id)
    int c = tid & 63;  // lane
    int row = blockIdx.x * 4 + r;
    float v = 0.f;
    if (row < n) v = in[row * 64 + c];
    if (relu_in) v = fmaxf(v, 0.f);
    sIn[r][c] = v;
    __syncthreads();
    float acc = 0.f;
#pragma unroll
    for (int k = 0; k < 64; k++) acc = fmaf(sIn[r][k], sW[k * 64 + c], acc);
    if (row < n) out[row * 64 + c] = acc;
}

// acc[n,c] = b[c] + t[n,c]*dinv[n]^2 + sum_{edges->n} t[rec.src,c]*rec.norm
// One wave per node, lane = channel. Coalesced 256B gather per edge.
__global__ void aggregate(const float* __restrict__ t, const int* __restrict__ offs,
                          const int2* __restrict__ rec,
                          const float* __restrict__ dinv, const float* __restrict__ bias,
                          float* __restrict__ acc, int n) {
    int wave = (blockIdx.x * blockDim.x + threadIdx.x) >> 6;
    int lane = threadIdx.x & 63;
    if (wave >= n) return;
    int beg = offs[wave], end = offs[wave + 1];
    float d = dinv[wave];
    float s = fmaf(t[wave * 64 + lane], d * d, bias[lane]);
    int j = beg;
    for (; j + 4 <= end; j += 4) {
        int2 e0 = rec[j], e1 = rec[j + 1], e2 = rec[j + 2], e3 = rec[j + 3];
        float v0 = t[e0.x * 64 + lane];
        float v1 = t[e1.x * 64 + lane];
        float v2 = t[e2.x * 64 + lane];
        float v3 = t[e3.x * 64 + lane];
        s = fmaf(v0, __int_as_float(e0.y), s);
        s = fmaf(v1, __int_as_float(e1.y), s);
        s = fmaf(v2, __int_as_float(e2.y), s);
        s = fmaf(v3, __int_as_float(e3.y), s);
    }
    for (; j < end; j++) {
        int2 e = rec[j];
        s = fmaf(t[e.x * 64 + lane], __int_as_float(e.y), s);
    }
    acc[wave * 64 + lane] = s;
}

// out[n,0:32] = relu(in)[n,0:64] @ Wlin(64x32) + blin. 8 rows/block.
__global__ void gemm32(const float* __restrict__ in, const float* __restrict__ W,
                       const float* __restrict__ b, float* __restrict__ out, int n) {
    __shared__ float sW[64 * 32];
    __shared__ float sIn[8][64];
    int tid = threadIdx.x;
    for (int i = tid; i < 64 * 32; i += 256) sW[i] = W[i];
    for (int i = tid; i < 8 * 64; i += 256) {
        int rr = i >> 6, cc = i & 63;
        int g = blockIdx.x * 8 + rr;
        float v = (g < n) ? in[g * 64 + cc] : 0.f;
        sIn[rr][cc] = fmaxf(v, 0.f);
    }
    __syncthreads();
    int r = tid >> 5, c = tid & 31;
    int row = blockIdx.x * 8 + r;
    float acc = b[c];
#pragma unroll
    for (int k = 0; k < 64; k++) acc = fmaf(sIn[r][k], sW[k * 32 + c], acc);
    if (row < n) out[row * 32 + c] = acc;
}

extern "C" void kernel_launch(void* const* d_in, const int* in_sizes, int n_in,
                              void* d_out, int out_size, void* d_ws, size_t ws_size,
                              hipStream_t stream) {
    (void)n_in; (void)out_size; (void)ws_size;
    const float* x    = (const float*)d_in[0];
    const void*  ei   = d_in[1];
    const float* W1   = (const float*)d_in[2];
    const float* b1   = (const float*)d_in[3];
    const float* W2   = (const float*)d_in[4];
    const float* b2   = (const float*)d_in[5];
    const float* Wlin = (const float*)d_in[6];
    const float* blin = (const float*)d_in[7];
    float* out = (float*)d_out;

    const int N = in_sizes[0] / IN_C;
    const int E = in_sizes[1] / 2;
    const int NB = (N + SCAN_CHUNK - 1) / SCAN_CHUNK;

    // Workspace layout (256B-aligned chunks), total ~66 MB.
    char* ws = (char*)d_ws;
    size_t off = 0;
    auto alloc = [&](size_t bytes) -> void* {
        size_t a = (off + 255) & ~(size_t)255;
        off = a + bytes;
        return (void*)(ws + a);
    };
    int*   flag   = (int*)  alloc(4);
    int*   deg    = (int*)  alloc((size_t)N * 4);
    int*   offs   = (int*)  alloc((size_t)(N + 1) * 4);
    int*   cursor = (int*)  alloc((size_t)N * 4);
    float* dinv   = (float*)alloc((size_t)N * 4);
    int*   bsum   = (int*)  alloc((size_t)NB * 4);
    int*   bpre   = (int*)  alloc((size_t)NB * 4);
    int2*  rec    = (int2*) alloc((size_t)E * 8);
    float* tbuf   = (float*)alloc((size_t)N * HID_C * 4);
    float* acc    = (float*)alloc((size_t)N * HID_C * 4);

    hipMemsetAsync(deg, 0, (size_t)N * 4, stream);

    int n_check = E < 4096 ? E : 4096;
    detect_fmt<<<1, 256, 0, stream>>>((const int*)ei, flag, n_check);
    count_deg<<<(E + 255) / 256, 256, 0, stream>>>(ei, E, flag, deg);
    block_sums<<<NB, 256, 0, stream>>>(deg, bsum, N);
    scan_bsums<<<1, 1024, 0, stream>>>(bsum, bpre, offs, NB, N);
    write_offs<<<NB, 256, 0, stream>>>(deg, bpre, offs, cursor, dinv, N);
    place_edges<<<(E + 255) / 256, 256, 0, stream>>>(ei, E, flag, cursor, dinv, rec);

    gemm64<<<(N + 3) / 4, 256, 0, stream>>>(x, W1, tbuf, N, 0);
    aggregate<<<(N + 3) / 4, 256, 0, stream>>>(tbuf, offs, rec, dinv, b1, acc, N);
    gemm64<<<(N + 3) / 4, 256, 0, stream>>>(acc, W2, tbuf, N, 1);
    aggregate<<<(N + 3) / 4, 256, 0, stream>>>(tbuf, offs, rec, dinv, b2, acc, N);
    gemm32<<<(N + 7) / 8, 256, 0, stream>>>(acc, Wlin, blin, out, N);
}